// Round 6
// baseline (190.858 us; speedup 1.0000x reference)
//
#include <hip/hip_runtime.h>
#include <math.h>

#define BB 4
#define NN 1024
#define MM 1024
#define HH 64
#define NT 8              // n-tiles
#define BN 128            // n per block
#define BM 64             // m per block
#define MT (MM / BM)      // 16 m-tiles

// amplification factors (measurement round; arithmetic-neutral)
#define REPS_FUSED 8
#define REPS_PREP 16
#define REPS_COMB 24

static constexpr float NEG_BIG = -3.0e38f;
static constexpr float SCALE = -0.72134752044448170f;   // -0.5 * log2(e)

__device__ __forceinline__ int opaque_zero() {
    int z;
    asm volatile("s_mov_b32 %0, 0" : "=s"(z));
    return z;
}

// ---------------- Kernel 1: fused prep (K-MLP, Q-MLP, vhat = V.Wo) ----------------
__global__ __launch_bounds__(256)
void prep_kernel(const float* __restrict__ coords_f,
                 const float* __restrict__ values_f,
                 const float* __restrict__ coords_t,
                 const float* __restrict__ Wk1, const float* __restrict__ bk1,
                 const float* __restrict__ Wk2, const float* __restrict__ bk2,
                 const float* __restrict__ Wq1, const float* __restrict__ bq1,
                 const float* __restrict__ Wq2, const float* __restrict__ bq2,
                 const float* __restrict__ Wv1, const float* __restrict__ bv1,
                 const float* __restrict__ Wv2, const float* __restrict__ bv2,
                 const float* __restrict__ Wo,
                 float* __restrict__ Kout, float* __restrict__ Qout,
                 float* __restrict__ vhat,
                 int reps, float inv_reps) {
    const int bx = blockIdx.x;
    const int tid = threadIdx.x;

    if (bx < 256) {
        const int type = bx >> 7;                 // 0 = K, 1 = Q
        const int sub = bx & 127;
        const int row = (sub >> 3) * 256 + tid;   // 0..4095
        const int co  = (sub & 7) * 8;

        const float* in = type ? coords_t : coords_f;
        const float* W1 = type ? Wq1 : Wk1;
        const float* b1 = type ? bq1 : bk1;
        const float* W2 = type ? Wq2 : Wk2;
        const float* b2 = type ? bq2 : bk2;
        float* out = type ? Qout : Kout;

        const float in0 = in[row * 3 + 0];
        const float in1 = in[row * 3 + 1];
        const float in2 = in[row * 3 + 2];

        float acc[8];
#pragma unroll
        for (int j = 0; j < 8; ++j) acc[j] = 0.0f;

        for (int rep = 0; rep < reps; ++rep) {
            const int zz = opaque_zero();         // blocks load hoisting across reps
            const float* W1r = W1 + zz;
            const float* b1r = b1 + zz;
            const float* W2r = W2 + zz;
            for (int hi = 0; hi < HH; ++hi) {
                float h = b1r[hi];
                h = fmaf(in0, W1r[hi], h);
                h = fmaf(in1, W1r[64 + hi], h);
                h = fmaf(in2, W1r[128 + hi], h);
                h = fmaxf(h, 0.0f);
                const float* w = W2r + hi * 64 + co;   // uniform -> scalar loads
#pragma unroll
                for (int j = 0; j < 8; ++j) acc[j] = fmaf(h, w[j], acc[j]);
            }
        }
#pragma unroll
        for (int j = 0; j < 8; ++j) out[row * 64 + co + j] = acc[j] * inv_reps + b2[co + j];
    } else {
        const int sub = bx - 256;                 // 0..15
        __shared__ float w2o[64];
        __shared__ float b2o_sh;
        if (tid < 64) {
            float s = 0.0f;
            for (int ho = 0; ho < 64; ++ho) s = fmaf(Wv2[tid * 64 + ho], Wo[ho], s);
            w2o[tid] = s;
        }
        if (tid == 0) {
            float s = 0.0f;
            for (int ho = 0; ho < 64; ++ho) s = fmaf(bv2[ho], Wo[ho], s);
            b2o_sh = s;
        }
        __syncthreads();

        const int row = sub * 256 + tid;
        const float* vin = values_f + row * 5;
        const float i0 = vin[0], i1 = vin[1], i2 = vin[2], i3 = vin[3], i4 = vin[4];

        float sacc = 0.0f;
        for (int rep = 0; rep < reps; ++rep) {
            const int zz = opaque_zero();
            const float* Wv1r = Wv1 + zz;
            const float* bv1r = bv1 + zz;
            for (int j = 0; j < HH; ++j) {
                float h = bv1r[j];
                h = fmaf(i0, Wv1r[j], h);
                h = fmaf(i1, Wv1r[64 + j], h);
                h = fmaf(i2, Wv1r[128 + j], h);
                h = fmaf(i3, Wv1r[192 + j], h);
                h = fmaf(i4, Wv1r[256 + j], h);
                h = fmaxf(h, 0.0f);
                sacc = fmaf(h, w2o[j], sacc);
            }
        }
        vhat[row] = sacc * inv_reps + b2o_sh;
    }
}

// ---------------- Kernel 2: GEMM-tiled L1-dist + in-block softmax partials ----------------
// grid (NT=8, MT=16, BB=4) = 512 blocks, 256 threads. (R4 config, +rep amplification)
__global__ __launch_bounds__(256)
void fused_kernel(const float* __restrict__ Kb,
                  const float* __restrict__ Qb,
                  const float* __restrict__ vh,
                  float* __restrict__ mxp,
                  float* __restrict__ denp,
                  float* __restrict__ nump,
                  int reps, float inv_reps) {
    __shared__ float kt[BN * 64];   // 32 KB, swizzled; reused as reduction buffer
    __shared__ float qt[BM * 64];   // 16 KB, swizzled

    const int tid = threadIdx.x;
    const int nt = blockIdx.x, mt = blockIdx.y, b = blockIdx.z;
    const int n0 = nt * BN, m0 = mt * BM;
    const int ty = tid >> 4, tx = tid & 15;

    float4* kt4 = reinterpret_cast<float4*>(kt);
    float4* qt4 = reinterpret_cast<float4*>(qt);

    {
        const float4* ksrc = reinterpret_cast<const float4*>(Kb + (b * NN + n0) * 64);
#pragma unroll
        for (int l = 0; l < 8; ++l) {
            const int fidx = l * 256 + tid;
            const int row = fidx >> 4, h4 = fidx & 15;
            kt4[row * 16 + (h4 ^ (row & 7))] = ksrc[fidx];
        }
        const float4* qsrc = reinterpret_cast<const float4*>(Qb + (b * MM + m0) * 64);
#pragma unroll
        for (int l = 0; l < 4; ++l) {
            const int fidx = l * 256 + tid;
            const int row = fidx >> 4, h4 = fidx & 15;
            qt4[row * 16 + (h4 ^ (row & 7))] = qsrc[fidx];
        }
    }
    __syncthreads();

    const int swk = ty & 7;
    const int swq = tx & 7;

    float acc[8][4];
#pragma unroll
    for (int i = 0; i < 8; ++i)
#pragma unroll
        for (int j = 0; j < 4; ++j) acc[i][j] = 0.0f;

    for (int rep = 0; rep < reps; ++rep) {
#pragma unroll 2
        for (int h4 = 0; h4 < 16; ++h4) {
            float4 kv[8], qv[4];
#pragma unroll
            for (int ni = 0; ni < 8; ++ni)
                kv[ni] = kt4[(ni * 16 + ty) * 16 + (h4 ^ swk)];
#pragma unroll
            for (int mj = 0; mj < 4; ++mj)
                qv[mj] = qt4[(mj * 16 + tx) * 16 + (h4 ^ swq)];
#pragma unroll
            for (int ni = 0; ni < 8; ++ni)
#pragma unroll
                for (int mj = 0; mj < 4; ++mj) {
                    acc[ni][mj] += fabsf(kv[ni].x - qv[mj].x);
                    acc[ni][mj] += fabsf(kv[ni].y - qv[mj].y);
                    acc[ni][mj] += fabsf(kv[ni].z - qv[mj].z);
                    acc[ni][mj] += fabsf(kv[ni].w - qv[mj].w);
                }
        }
    }

    float vloc[8];
#pragma unroll
    for (int ni = 0; ni < 8; ++ni) vloc[ni] = vh[b * NN + n0 + ni * 16 + ty];

    float mxr[4], denr[4], numr[4];
#pragma unroll
    for (int mj = 0; mj < 4; ++mj) {
        float a[8];
#pragma unroll
        for (int ni = 0; ni < 8; ++ni) {
            const float d = acc[ni][mj] * inv_reps;
            a[ni] = d * d * SCALE;
        }
        const float mx = fmaxf(fmaxf(fmaxf(a[0], a[1]), fmaxf(a[2], a[3])),
                               fmaxf(fmaxf(a[4], a[5]), fmaxf(a[6], a[7])));
        float den = 0.0f, num = 0.0f;
#pragma unroll
        for (int ni = 0; ni < 8; ++ni) {
            const float p = __builtin_amdgcn_exp2f(a[ni] - mx);
            den += p;
            num = fmaf(p, vloc[ni], num);
        }
        mxr[mj] = mx; denr[mj] = den; numr[mj] = num;
    }

    __syncthreads();
    float* red = kt;          // 16*64*3 floats = 12 KB, aliases kt
#pragma unroll
    for (int mj = 0; mj < 4; ++mj) {
        const int base = (ty * 64 + mj * 16 + tx) * 3;
        red[base + 0] = mxr[mj];
        red[base + 1] = denr[mj];
        red[base + 2] = numr[mj];
    }
    __syncthreads();

    if (tid < 64) {
        float M = NEG_BIG, D = 0.0f, Nu = 0.0f;
        for (int t = 0; t < 16; ++t) {
            const int base = (t * 64 + tid) * 3;
            const float m2 = red[base + 0];
            const float d2 = red[base + 1];
            const float n2 = red[base + 2];
            const float nm = fmaxf(M, m2);
            const float s0 = __builtin_amdgcn_exp2f(M - nm);
            const float s1 = __builtin_amdgcn_exp2f(m2 - nm);
            D  = D * s0 + d2 * s1;
            Nu = Nu * s0 + n2 * s1;
            M = nm;
        }
        const int p = nt * (BB * MM) + b * MM + m0 + tid;
        mxp[p] = M; denp[p] = D; nump[p] = Nu;
    }
}

// ---------------- Kernel 3: combine n-tile partials ----------------
// grid 64 x 64: thread per (b,m). (amplified x REPS_COMB)
__global__ __launch_bounds__(64)
void combine_kernel(const float* __restrict__ mxp,
                    const float* __restrict__ denp,
                    const float* __restrict__ nump,
                    const float* __restrict__ bo,
                    float* __restrict__ out,
                    int reps) {
    const int bm = blockIdx.x * 64 + threadIdx.x;   // b*MM + m
    float accD = 0.0f, accN = 0.0f;
    for (int rep = 0; rep < reps; ++rep) {
        const int zz = opaque_zero();               // force re-load each rep
        float M = NEG_BIG, D = 0.0f, Nu = 0.0f;
#pragma unroll
        for (int nt = 0; nt < NT; ++nt) {
            const int idx = nt * (BB * MM) + bm + zz;
            const float m2 = mxp[idx];
            const float d2 = denp[idx];
            const float n2 = nump[idx];
            const float nm = fmaxf(M, m2);
            const float s0 = __builtin_amdgcn_exp2f(M - nm);
            const float s1 = __builtin_amdgcn_exp2f(m2 - nm);
            D  = D * s0 + d2 * s1;
            Nu = Nu * s0 + n2 * s1;
            M = nm;
        }
        accD += D;
        accN += Nu;
    }
    out[bm] = accN / accD + bo[0];                  // (R*Nu)/(R*D) == Nu/D
}

// ---------------- launcher ----------------
extern "C" void kernel_launch(void* const* d_in, const int* in_sizes, int n_in,
                              void* d_out, int out_size, void* d_ws, size_t ws_size,
                              hipStream_t stream) {
    const float* coords_f = (const float*)d_in[0];
    const float* values_f = (const float*)d_in[1];
    const float* coords_t = (const float*)d_in[2];
    const float* Wk1 = (const float*)d_in[3];
    const float* bk1 = (const float*)d_in[4];
    const float* Wk2 = (const float*)d_in[5];
    const float* bk2 = (const float*)d_in[6];
    const float* Wq1 = (const float*)d_in[7];
    const float* bq1 = (const float*)d_in[8];
    const float* Wq2 = (const float*)d_in[9];
    const float* bq2 = (const float*)d_in[10];
    const float* Wv1 = (const float*)d_in[11];
    const float* bv1 = (const float*)d_in[12];
    const float* Wv2 = (const float*)d_in[13];
    const float* bv2 = (const float*)d_in[14];
    const float* Wo  = (const float*)d_in[15];
    const float* bo  = (const float*)d_in[16];

    float* ws  = (float*)d_ws;
    float* Kb  = ws;                      // B*N*H = 262144
    float* Qb  = Kb + BB * NN * HH;       // 262144
    float* vh  = Qb + BB * MM * HH;       // 4096
    float* mxp = vh + BB * NN;            // NT*B*M = 32768
    float* denp = mxp + NT * BB * MM;
    float* nump = denp + NT * BB * MM;

    prep_kernel<<<dim3(272), 256, 0, stream>>>(
        coords_f, values_f, coords_t,
        Wk1, bk1, Wk2, bk2, Wq1, bq1, Wq2, bq2,
        Wv1, bv1, Wv2, bv2, Wo, Kb, Qb, vh,
        REPS_PREP, 1.0f / REPS_PREP);

    fused_kernel<<<dim3(NT, MT, BB), 256, 0, stream>>>(
        Kb, Qb, vh, mxp, denp, nump, REPS_FUSED, 1.0f / REPS_FUSED);

    combine_kernel<<<dim3(64), 64, 0, stream>>>(
        mxp, denp, nump, bo, (float*)d_out, REPS_COMB);
}

// Round 7
// 27.142 us; speedup vs baseline: 7.0319x; 7.0319x over previous
//
#include <hip/hip_runtime.h>
#include <math.h>

#define BB 4
#define NN 1024
#define MM 1024
#define HH 64
#define NT 8              // n-tiles
#define BN 128            // n per block
#define BM 64             // m per block
#define MT (MM / BM)      // 16 m-tiles

static constexpr float NEG_BIG = -3.0e38f;
static constexpr float SCALE = -0.72134752044448170f;   // -0.5 * log2(e)

// ---------------- Kernel 1: fused prep (K-MLP, Q-MLP, vhat = V.Wo) ----------------
__global__ __launch_bounds__(256)
void prep_kernel(const float* __restrict__ coords_f,
                 const float* __restrict__ values_f,
                 const float* __restrict__ coords_t,
                 const float* __restrict__ Wk1, const float* __restrict__ bk1,
                 const float* __restrict__ Wk2, const float* __restrict__ bk2,
                 const float* __restrict__ Wq1, const float* __restrict__ bq1,
                 const float* __restrict__ Wq2, const float* __restrict__ bq2,
                 const float* __restrict__ Wv1, const float* __restrict__ bv1,
                 const float* __restrict__ Wv2, const float* __restrict__ bv2,
                 const float* __restrict__ Wo,
                 float* __restrict__ Kout, float* __restrict__ Qout,
                 float* __restrict__ vhat) {
    const int bx = blockIdx.x;
    const int tid = threadIdx.x;

    if (bx < 256) {
        const int type = bx >> 7;                 // 0 = K, 1 = Q
        const int sub = bx & 127;
        const int row = (sub >> 3) * 256 + tid;   // 0..4095
        const int co  = (sub & 7) * 8;

        const float* in = type ? coords_t : coords_f;
        const float* W1 = type ? Wq1 : Wk1;
        const float* b1 = type ? bq1 : bk1;
        const float* W2 = type ? Wq2 : Wk2;
        const float* b2 = type ? bq2 : bk2;
        float* out = type ? Qout : Kout;

        const float in0 = in[row * 3 + 0];
        const float in1 = in[row * 3 + 1];
        const float in2 = in[row * 3 + 2];

        float acc[8];
#pragma unroll
        for (int j = 0; j < 8; ++j) acc[j] = b2[co + j];

        for (int hi = 0; hi < HH; ++hi) {
            float h = b1[hi];
            h = fmaf(in0, W1[hi], h);
            h = fmaf(in1, W1[64 + hi], h);
            h = fmaf(in2, W1[128 + hi], h);
            h = fmaxf(h, 0.0f);
            const float* w = W2 + hi * 64 + co;    // uniform -> scalar loads
#pragma unroll
            for (int j = 0; j < 8; ++j) acc[j] = fmaf(h, w[j], acc[j]);
        }
#pragma unroll
        for (int j = 0; j < 8; ++j) out[row * 64 + co + j] = acc[j];
    } else {
        const int sub = bx - 256;                 // 0..15
        __shared__ float w2o[64];
        __shared__ float b2o_sh;
        if (tid < 64) {
            float s = 0.0f;
            for (int ho = 0; ho < 64; ++ho) s = fmaf(Wv2[tid * 64 + ho], Wo[ho], s);
            w2o[tid] = s;
        }
        if (tid == 0) {
            float s = 0.0f;
            for (int ho = 0; ho < 64; ++ho) s = fmaf(bv2[ho], Wo[ho], s);
            b2o_sh = s;
        }
        __syncthreads();

        const int row = sub * 256 + tid;
        const float* vin = values_f + row * 5;
        const float i0 = vin[0], i1 = vin[1], i2 = vin[2], i3 = vin[3], i4 = vin[4];

        float s = b2o_sh;
        for (int j = 0; j < HH; ++j) {
            float h = bv1[j];
            h = fmaf(i0, Wv1[j], h);
            h = fmaf(i1, Wv1[64 + j], h);
            h = fmaf(i2, Wv1[128 + j], h);
            h = fmaf(i3, Wv1[192 + j], h);
            h = fmaf(i4, Wv1[256 + j], h);
            h = fmaxf(h, 0.0f);
            s = fmaf(h, w2o[j], s);
        }
        vhat[row] = s;
    }
}

// ---------------- Kernel 2: GEMM-tiled L1-dist + in-block softmax partials ----------------
// grid (NT=8, MT=16, BB=4) = 512 blocks, 256 threads, 48 KB LDS (2 blocks/CU).
// __launch_bounds__(256, 2): cap at 2 waves/SIMD -> VGPR budget 256, so
// kv[8]+qv[4]+acc[32] stay live (R6 showed VGPR=68 strangled the loop: 2.3x VALU inflation).
// h4 loop fully unrolled -> LDS offsets fold to per-thread base + constants.
__global__ __launch_bounds__(256, 2)
void fused_kernel(const float* __restrict__ Kb,
                  const float* __restrict__ Qb,
                  const float* __restrict__ vh,
                  float* __restrict__ mxp,
                  float* __restrict__ denp,
                  float* __restrict__ nump) {
    __shared__ float kt[BN * 64];   // 32 KB, swizzled; reused as reduction buffer
    __shared__ float qt[BM * 64];   // 16 KB, swizzled

    const int tid = threadIdx.x;
    const int nt = blockIdx.x, mt = blockIdx.y, b = blockIdx.z;
    const int n0 = nt * BN, m0 = mt * BM;
    const int ty = tid >> 4, tx = tid & 15;

    float4* kt4 = reinterpret_cast<float4*>(kt);
    float4* qt4 = reinterpret_cast<float4*>(qt);

    {
        const float4* ksrc = reinterpret_cast<const float4*>(Kb + (b * NN + n0) * 64);
#pragma unroll
        for (int l = 0; l < 8; ++l) {
            const int fidx = l * 256 + tid;
            const int row = fidx >> 4, h4 = fidx & 15;
            kt4[row * 16 + (h4 ^ (row & 7))] = ksrc[fidx];
        }
        const float4* qsrc = reinterpret_cast<const float4*>(Qb + (b * MM + m0) * 64);
#pragma unroll
        for (int l = 0; l < 4; ++l) {
            const int fidx = l * 256 + tid;
            const int row = fidx >> 4, h4 = fidx & 15;
            qt4[row * 16 + (h4 ^ (row & 7))] = qsrc[fidx];
        }
    }
    __syncthreads();

    const int swk = ty & 7;
    const int swq = tx & 7;

    // per-thread base pointers (hoisted)
    const float4* kbase = kt4 + ty * 16;    // + ni*256 + (h4^swk)
    const float4* qbase = qt4 + tx * 16;    // + mj*256 + (h4^swq)

    float acc[8][4];
#pragma unroll
    for (int i = 0; i < 8; ++i)
#pragma unroll
        for (int j = 0; j < 4; ++j) acc[i][j] = 0.0f;

#pragma unroll
    for (int h4 = 0; h4 < 16; ++h4) {
        float4 kv[8], qv[4];
        const int ck = h4 ^ swk;
        const int cq = h4 ^ swq;
#pragma unroll
        for (int ni = 0; ni < 8; ++ni)
            kv[ni] = kbase[ni * 256 + ck];
#pragma unroll
        for (int mj = 0; mj < 4; ++mj)
            qv[mj] = qbase[mj * 256 + cq];
#pragma unroll
        for (int ni = 0; ni < 8; ++ni)
#pragma unroll
            for (int mj = 0; mj < 4; ++mj) {
                acc[ni][mj] += fabsf(kv[ni].x - qv[mj].x);
                acc[ni][mj] += fabsf(kv[ni].y - qv[mj].y);
                acc[ni][mj] += fabsf(kv[ni].z - qv[mj].z);
                acc[ni][mj] += fabsf(kv[ni].w - qv[mj].w);
            }
    }

    float vloc[8];
#pragma unroll
    for (int ni = 0; ni < 8; ++ni) vloc[ni] = vh[b * NN + n0 + ni * 16 + ty];

    // per-thread two-pass softmax over its 8 n's, for each of its 4 m's
    float mxr[4], denr[4], numr[4];
#pragma unroll
    for (int mj = 0; mj < 4; ++mj) {
        float a[8];
#pragma unroll
        for (int ni = 0; ni < 8; ++ni) {
            const float d = acc[ni][mj];
            a[ni] = d * d * SCALE;
        }
        const float mx = fmaxf(fmaxf(fmaxf(a[0], a[1]), fmaxf(a[2], a[3])),
                               fmaxf(fmaxf(a[4], a[5]), fmaxf(a[6], a[7])));
        float den = 0.0f, num = 0.0f;
#pragma unroll
        for (int ni = 0; ni < 8; ++ni) {
            const float p = __builtin_amdgcn_exp2f(a[ni] - mx);
            den += p;
            num = fmaf(p, vloc[ni], num);
        }
        mxr[mj] = mx; denr[mj] = den; numr[mj] = num;
    }

    // cross-thread (over ty) reduction in LDS: red[ty][mcol][3] (12 KB, aliases kt)
    __syncthreads();
    float* red = kt;
#pragma unroll
    for (int mj = 0; mj < 4; ++mj) {
        const int base = (ty * 64 + mj * 16 + tx) * 3;
        red[base + 0] = mxr[mj];
        red[base + 1] = denr[mj];
        red[base + 2] = numr[mj];
    }
    __syncthreads();

    if (tid < 64) {
        float M = NEG_BIG, D = 0.0f, Nu = 0.0f;
        for (int t = 0; t < 16; ++t) {
            const int base = (t * 64 + tid) * 3;
            const float m2 = red[base + 0];
            const float d2 = red[base + 1];
            const float n2 = red[base + 2];
            const float nm = fmaxf(M, m2);
            const float s0 = __builtin_amdgcn_exp2f(M - nm);
            const float s1 = __builtin_amdgcn_exp2f(m2 - nm);
            D  = D * s0 + d2 * s1;
            Nu = Nu * s0 + n2 * s1;
            M = nm;
        }
        const int p = nt * (BB * MM) + b * MM + m0 + tid;
        mxp[p] = M; denp[p] = D; nump[p] = Nu;
    }
}

// ---------------- Kernel 3: combine n-tile partials ----------------
// grid 64 x 64: thread per (b,m).
__global__ __launch_bounds__(64)
void combine_kernel(const float* __restrict__ mxp,
                    const float* __restrict__ denp,
                    const float* __restrict__ nump,
                    const float* __restrict__ bo,
                    float* __restrict__ out) {
    const int bm = blockIdx.x * 64 + threadIdx.x;   // b*MM + m
    float M = NEG_BIG, D = 0.0f, Nu = 0.0f;
#pragma unroll
    for (int nt = 0; nt < NT; ++nt) {
        const int idx = nt * (BB * MM) + bm;
        const float m2 = mxp[idx];
        const float d2 = denp[idx];
        const float n2 = nump[idx];
        const float nm = fmaxf(M, m2);
        const float s0 = __builtin_amdgcn_exp2f(M - nm);
        const float s1 = __builtin_amdgcn_exp2f(m2 - nm);
        D  = D * s0 + d2 * s1;
        Nu = Nu * s0 + n2 * s1;
        M = nm;
    }
    out[bm] = Nu / D + bo[0];
}

// ---------------- launcher ----------------
extern "C" void kernel_launch(void* const* d_in, const int* in_sizes, int n_in,
                              void* d_out, int out_size, void* d_ws, size_t ws_size,
                              hipStream_t stream) {
    const float* coords_f = (const float*)d_in[0];
    const float* values_f = (const float*)d_in[1];
    const float* coords_t = (const float*)d_in[2];
    const float* Wk1 = (const float*)d_in[3];
    const float* bk1 = (const float*)d_in[4];
    const float* Wk2 = (const float*)d_in[5];
    const float* bk2 = (const float*)d_in[6];
    const float* Wq1 = (const float*)d_in[7];
    const float* bq1 = (const float*)d_in[8];
    const float* Wq2 = (const float*)d_in[9];
    const float* bq2 = (const float*)d_in[10];
    const float* Wv1 = (const float*)d_in[11];
    const float* bv1 = (const float*)d_in[12];
    const float* Wv2 = (const float*)d_in[13];
    const float* bv2 = (const float*)d_in[14];
    const float* Wo  = (const float*)d_in[15];
    const float* bo  = (const float*)d_in[16];

    float* ws  = (float*)d_ws;
    float* Kb  = ws;                      // B*N*H = 262144
    float* Qb  = Kb + BB * NN * HH;       // 262144
    float* vh  = Qb + BB * MM * HH;       // 4096
    float* mxp = vh + BB * NN;            // NT*B*M = 32768
    float* denp = mxp + NT * BB * MM;
    float* nump = denp + NT * BB * MM;

    prep_kernel<<<dim3(272), 256, 0, stream>>>(
        coords_f, values_f, coords_t,
        Wk1, bk1, Wk2, bk2, Wq1, bq1, Wq2, bq2,
        Wv1, bv1, Wv2, bv2, Wo, Kb, Qb, vh);

    fused_kernel<<<dim3(NT, MT, BB), 256, 0, stream>>>(
        Kb, Qb, vh, mxp, denp, nump);

    combine_kernel<<<dim3(64), 64, 0, stream>>>(
        mxp, denp, nump, bo, (float*)d_out);
}